// Round 14
// baseline (458.368 us; speedup 1.0000x reference)
//
#include <hip/hip_runtime.h>
#include <hip/hip_bf16.h>

// ---------------------------------------------------------------------------
// AttentionBlock: qkv-proj (+LN on q,k) -> masked flash attention -> out-proj
// B=2, S=2048, E=2048, H=16, D=128.
// GEMMs: k_gemm4 — 128x256 tile, BK=64, 4 waves, per-wave output 128x64
// (0.375 ds_reads/MFMA, the m201 intensity), tri-buffered counted-vmcnt
// pipeline, XCD-clustered (each XCD owns one B-panel -> L2-resident).
// Attention: bf16 MFMA 32x32x16, swapped QK^T, exp2-domain softmax, dbuf,
// XCD-clustered (K/V working set 4MB = L2 per XCD).
// V^T produced directly by swapped-operand GEMM (MODE 4, key-perm store).
// ---------------------------------------------------------------------------

typedef __attribute__((ext_vector_type(8))) __bf16 bf16x8;
typedef __attribute__((ext_vector_type(4))) float f32x4;
typedef __attribute__((ext_vector_type(16))) float f32x16;
typedef __attribute__((ext_vector_type(8))) unsigned short ushort8;
typedef __attribute__((ext_vector_type(4))) unsigned short ushort4v;
typedef __attribute__((ext_vector_type(4))) unsigned uint4v;
typedef __attribute__((ext_vector_type(4))) float float4v;

#define MFMA16(a, b, c) __builtin_amdgcn_mfma_f32_16x16x32_bf16((a), (b), (c), 0, 0, 0)
#define MFMA32(a, b, c) __builtin_amdgcn_mfma_f32_32x32x16_bf16((a), (b), (c), 0, 0, 0)

__device__ __forceinline__ unsigned short f2bf(float f) {
  unsigned u = __builtin_bit_cast(unsigned, f);
  u += 0x7fffu + ((u >> 16) & 1u);           // RNE
  return (unsigned short)(u >> 16);
}

__device__ __forceinline__ unsigned pkbf(float lo, float hi) {  // bf16(lo)|bf16(hi)<<16
  unsigned d;
  asm("v_cvt_pk_bf16_f32 %0, %1, %2" : "=v"(d) : "v"(lo), "v"(hi));
  return d;
}

__device__ __forceinline__ float max3f(float a, float b, float c) {
  float d;
  asm("v_max3_f32 %0, %1, %2, %3" : "=v"(d) : "v"(a), "v"(b), "v"(c));
  return d;
}

__device__ __forceinline__ float exp2a(float x) {  // 2^x
  float d;
  asm("v_exp_f32 %0, %1" : "=v"(d) : "v"(x));
  return d;
}

__device__ __forceinline__ void gload_lds16(const void* g, void* l) {
  __builtin_amdgcn_global_load_lds(
      (const __attribute__((address_space(1))) void*)g,
      (__attribute__((address_space(3))) void*)l, 16, 0, 0);
}

// ---------------- prep (fused): q+q_pos, kv+kv_pos & kv, mask bitmask ------
__global__ __launch_bounds__(256) void k_prep(const float4v* __restrict__ q,
                                              const float4v* __restrict__ q_pos,
                                              const float4v* __restrict__ kv,
                                              const float4v* __restrict__ kv_pos,
                                              const int* __restrict__ mask,
                                              ushort4v* __restrict__ a_q,
                                              ushort4v* __restrict__ a_k,
                                              ushort4v* __restrict__ a_v,
                                              unsigned long long* __restrict__ mkb) {
  int bx = blockIdx.x, tid = threadIdx.x;
  if (bx < 8192) {
    int i = bx * 256 + tid;
    float4v a = q[i] + q_pos[i];
    ushort4v r;
    r[0] = f2bf(a[0]); r[1] = f2bf(a[1]); r[2] = f2bf(a[2]); r[3] = f2bf(a[3]);
    a_q[i] = r;
  } else if (bx < 16384) {
    int i = (bx - 8192) * 256 + tid;
    float4v a = kv[i];
    float4v s = a + kv_pos[i];
    ushort4v ra, rb;
    ra[0] = f2bf(s[0]); ra[1] = f2bf(s[1]); ra[2] = f2bf(s[2]); ra[3] = f2bf(s[3]);
    rb[0] = f2bf(a[0]); rb[1] = f2bf(a[1]); rb[2] = f2bf(a[2]); rb[3] = f2bf(a[3]);
    a_k[i] = ra; a_v[i] = rb;
  } else {
    int i = (bx - 16384) * 256 + tid;
    unsigned long long b = __ballot(mask[i] != 0);
    if ((tid & 63) == 0) mkb[i >> 6] = b;
  }
}

// ---------------- prep: weight transpose fp32[K][N] -> bf16[N][K] ----------
__global__ __launch_bounds__(256) void k_tr(const float* __restrict__ s0, const float* __restrict__ s1,
                                            const float* __restrict__ s2, const float* __restrict__ s3,
                                            unsigned short* __restrict__ d0, unsigned short* __restrict__ d1,
                                            unsigned short* __restrict__ d2, unsigned short* __restrict__ d3) {
  __shared__ float t[32][33];
  const float* S; unsigned short* D;
  switch (blockIdx.z) {
    case 0: S = s0; D = d0; break;
    case 1: S = s1; D = d1; break;
    case 2: S = s2; D = d2; break;
    default: S = s3; D = d3; break;
  }
  int x = threadIdx.x & 31, y = threadIdx.x >> 5;
  int r0 = blockIdx.y * 32, c0 = blockIdx.x * 32;
#pragma unroll
  for (int i = 0; i < 4; ++i) t[y + 8 * i][x] = S[(size_t)(r0 + y + 8 * i) * 2048 + c0 + x];
  __syncthreads();
#pragma unroll
  for (int i = 0; i < 4; ++i)
    D[(size_t)(c0 + y + 8 * i) * 2048 + r0 + x] = f2bf(t[x][y + 8 * i]);
}

// ---------------- GEMM v3: 128x256 tile, BK=64, 4 waves, tri-buffer --------
// Per-wave output 128x64 (av[8] x bv[4] per kk-half: 24 reads / 64 MFMA per
// K-tile = 0.375 reads/MFMA). Counted-vmcnt pipeline: tile t computing while
// t+1 landed and t+2 in flight (vmcnt(24) mid-loop; 12 loads/thread/tile).
// MODE 1: LN*scale*rsqrt(D)*log2e (Q) -> [B,H,S,D] bf16 (BN=256 = 2 heads)
// MODE 2: LN*scale (K)               -> [B,H,S,D] bf16
// MODE 3: fp32 direct to [M][2048] (final out-proj)
// MODE 4: V^T direct: A=wvt (M=2048=(h,d)), Bt=a_v (N=4096=(b,s));
//         store at Vtp[bh][d][(s&~15)|swap23(s&15)] bf16.
template <int MODE>
__global__ __launch_bounds__(256) void k_gemm4(const unsigned short* __restrict__ A,
                                               const unsigned short* __restrict__ Bt,
                                               void* __restrict__ Cv,
                                               const float* __restrict__ lnsc) {
  constexpr int K = 2048;
  constexpr int NT = 32;                 // K / 64
  constexpr int BUF = 49152;             // A 16KB + B 32KB per K-tile
  __shared__ __attribute__((aligned(16))) char smem[3 * BUF];  // 144 KB
  int tid = threadIdx.x;
  int lane = tid & 63, w = tid >> 6;     // 4 waves; wave w owns cols w*64..+63
  int r15 = lane & 15, blk = lane >> 4;
  // XCD-clustered remap: consecutive L round-robin XCDs; nt = L&7 puts all
  // blocks sharing a B-panel (1MB) on one XCD -> L2-resident.
  int L = blockIdx.y * gridDim.x + blockIdx.x;
  int mt, nt;
  if constexpr (MODE == 4) { nt = (L & 7) + 8 * ((L >> 3) & 1); mt = L >> 4; }  // 16n x 16m
  else { nt = L & 7; mt = L >> 3; }                                            // 8n x 32m
  int n0 = nt * 256, m0 = mt * 128;
  const unsigned short* Abase = A + (size_t)m0 * K;
  const unsigned short* Bbase = Bt + (size_t)n0 * K;
  f32x4 acc[8][4] = {};

  // per-thread staging descriptors (source XOR-pre-swizzled, dest linear)
  const unsigned short* ag[4]; int al[4];
  const unsigned short* bg[8]; int bl[8];
#pragma unroll
  for (int i = 0; i < 4; ++i) {
    int c = i * 256 + tid;               // 0..1023: A rows 0..127, 8 chunks/row
    int row = c >> 3, cc = c & 7;
    ag[i] = Abase + (size_t)row * K + ((cc ^ (row & 7)) * 8);
    al[i] = c * 16;
  }
#pragma unroll
  for (int i = 0; i < 8; ++i) {
    int c = i * 256 + tid;               // 0..2047: B rows 0..255
    int row = c >> 3, cc = c & 7;
    bg[i] = Bbase + (size_t)row * K + ((cc ^ (row & 7)) * 8);
    bl[i] = c * 16;
  }

  auto stage = [&](int t) {
    char* buf = smem + (t % 3) * BUF;
    int kt = t * 64;
#pragma unroll
    for (int i = 0; i < 4; ++i) gload_lds16(ag[i] + kt, buf + al[i]);
#pragma unroll
    for (int i = 0; i < 8; ++i) gload_lds16(bg[i] + kt, buf + 16384 + bl[i]);
  };

  stage(0);
  stage(1);

  for (int t = 0; t < NT; ++t) {
    if (t + 2 < NT) {
      stage(t + 2);                                      // 12 loads into buf[(t+2)%3]
      asm volatile("s_waitcnt vmcnt(24)" ::: "memory");  // tile t landed; t+1,t+2 in flight
    } else if (t + 1 < NT) {
      asm volatile("s_waitcnt vmcnt(12)" ::: "memory");  // tile t landed; t+1 in flight
    } else {
      asm volatile("s_waitcnt vmcnt(0)" ::: "memory");   // tail drain
    }
    __builtin_amdgcn_s_barrier();        // B1: all waves' tile-t loads drained
    __builtin_amdgcn_sched_barrier(0);
    const unsigned short* sA = (const unsigned short*)(smem + (t % 3) * BUF);
    const unsigned short* sB = (const unsigned short*)(smem + (t % 3) * BUF + 16384);
#pragma unroll
    for (int kk = 0; kk < 2; ++kk) {
      bf16x8 av[8], bv[4];
#pragma unroll
      for (int i = 0; i < 8; ++i) {
        int row = i * 16 + r15;
        av[i] = *(const bf16x8*)&sA[row * 64 + (((kk * 4 + blk) ^ (row & 7)) * 8)];
      }
#pragma unroll
      for (int j = 0; j < 4; ++j) {
        int row = w * 64 + j * 16 + r15;
        bv[j] = *(const bf16x8*)&sB[row * 64 + (((kk * 4 + blk) ^ (row & 7)) * 8)];
      }
#pragma unroll
      for (int i = 0; i < 8; ++i)
#pragma unroll
        for (int j = 0; j < 4; ++j) acc[i][j] = MFMA16(av[i], bv[j], acc[i][j]);
    }
    asm volatile("s_waitcnt lgkmcnt(0)" ::: "memory");  // my LDS reads done
    __builtin_amdgcn_s_barrier();        // B2: buf[t%3] safe to overwrite next iter
  }
  __syncthreads();                        // full fence before LDS reuse in epilogue

  if constexpr (MODE == 3) {
    float* C = (float*)Cv;
#pragma unroll
    for (int i = 0; i < 8; ++i)
#pragma unroll
      for (int r = 0; r < 4; ++r) {
        int rowl = i * 16 + blk * 4 + r;              // C row=(lane>>4)*4+reg
#pragma unroll
        for (int j = 0; j < 4; ++j) {
          int coll = w * 64 + j * 16 + r15;           // C col=lane&15
          C[(size_t)(m0 + rowl) * 2048 + n0 + coll] = acc[i][j][r];
        }
      }
  } else if constexpr (MODE == 4) {
    // V^T: rowg=(h,d), col=(b,s); key s stored at pos (s&~15)|swap23(r15)
    unsigned short* Vtp = (unsigned short*)Cv;
    int p15 = (r15 & 3) | ((r15 & 4) << 1) | ((r15 & 8) >> 1);
#pragma unroll
    for (int i = 0; i < 8; ++i)
#pragma unroll
      for (int r = 0; r < 4; ++r) {
        int rowg = m0 + i * 16 + blk * 4 + r;         // (h,d)
        int h = rowg >> 7, d = rowg & 127;
#pragma unroll
        for (int j = 0; j < 4; ++j) {
          int col = n0 + w * 64 + j * 16;             // (b, s&~15)
          int b = col >> 11, s16 = col & 2047;
          Vtp[(((size_t)(b * 16 + h) * 128 + d) * 2048) + s16 + p15] = f2bf(acc[i][j][r]);
        }
      }
  } else {
    // MODE 1/2: LayerNorm over head_dim=128; BN=256 spans 2 heads:
    // head = nt*2 + (w>>1); d = (w&1)*64 + j*16 + r15.
    float* sSum = (float*)smem;            // [4 waves][128 rows]
    float* sSq  = (float*)smem + 512;
#pragma unroll
    for (int i = 0; i < 8; ++i)
#pragma unroll
      for (int r = 0; r < 4; ++r) {
        float sm = 0.f, sq = 0.f;
#pragma unroll
        for (int j = 0; j < 4; ++j) { float v = acc[i][j][r]; sm += v; sq += v * v; }
        sm += __shfl_xor(sm, 1); sq += __shfl_xor(sq, 1);
        sm += __shfl_xor(sm, 2); sq += __shfl_xor(sq, 2);
        sm += __shfl_xor(sm, 4); sq += __shfl_xor(sq, 4);
        sm += __shfl_xor(sm, 8); sq += __shfl_xor(sq, 8);
        if (r15 == 0) {
          int rowl = i * 16 + blk * 4 + r;
          sSum[w * 128 + rowl] = sm;
          sSq[w * 128 + rowl] = sq;
        }
      }
    __syncthreads();
    unsigned short* Hout = (unsigned short*)Cv;
    int hw = w >> 1;
    int h = nt * 2 + hw;
#pragma unroll
    for (int i = 0; i < 8; ++i)
#pragma unroll
      for (int r = 0; r < 4; ++r) {
        int rowl = i * 16 + blk * 4 + r;
        float sm = sSum[hw * 256 + rowl] + sSum[hw * 256 + 128 + rowl];
        float sq = sSq[hw * 256 + rowl] + sSq[hw * 256 + 128 + rowl];
        float mean = sm * 0.0078125f;
        float var = sq * 0.0078125f - mean * mean;
        float rstd = rsqrtf(var + 1e-6f);
        int rowg = m0 + rowl;
        int b = rowg >> 11, s = rowg & 2047;
        unsigned short* orow = Hout + (((size_t)b * 16 + h) * 2048 + s) * 128;
#pragma unroll
        for (int j = 0; j < 4; ++j) {
          int d = (w & 1) * 64 + j * 16 + r15;
          float v = acc[i][j][r];
          // log2e folded in for Q: attention softmax runs in exp2 domain
          if constexpr (MODE == 1)
            v = (v - mean) * rstd * lnsc[d] * (0.08838834764831845f * 1.4426950408889634f);
          else
            v = (v - mean) * rstd * lnsc[d];
          orow[d] = f2bf(v);
        }
      }
  }
}

// ---------------- flash attention: 32x32x16 MFMA, XCD-clustered ------------
// 4 waves x 32 q = QBLK 128; KVBLK=64; dbuf 64 KB; grid 512 -> 2 blocks/CU.
// XCD k owns bh {4k..4k+3} (K/V working set 4MB = L2 per XCD).
__global__ __launch_bounds__(256, 2) void k_attn(const unsigned short* __restrict__ Qh,
                                                 const unsigned short* __restrict__ Kh,
                                                 const unsigned short* __restrict__ Vtp,
                                                 const unsigned* __restrict__ maskb,
                                                 unsigned short* __restrict__ O) {
  __shared__ __attribute__((aligned(16))) char smem[65536];  // 2 x (sK 16K + sV 16K)
  int tid = threadIdx.x, w = tid >> 6;
  int lane = tid & 63;
  int q31 = lane & 31, hi = lane >> 5;
  // XCD-clustered remap (bijective: grid = 16 x 32 = 512)
  int L = blockIdx.y * 16 + blockIdx.x;
  int xcd = L & 7, slot = L >> 3;        // slot 0..63
  int bh = xcd * 4 + (slot >> 4);
  int qb = (slot & 15) * 128;
  int b = bh >> 4, h = bh & 15;
  size_t base = (size_t)bh * (2048 * 128);
  int qrow = qb + w * 32 + q31;

  bf16x8 qf[8];  // Q (B-operand): col=q31, k-window wd: d = wd*16 + hi*8 + j
  {
    const unsigned short* qp = Qh + base + (size_t)qrow * 128 + hi * 8;
#pragma unroll
    for (int wd = 0; wd < 8; ++wd) qf[wd] = *(const bf16x8*)(qp + wd * 16);
  }
  const unsigned* mrow = maskb + ((size_t)b * 2048 + qrow) * 64;

  // staging bases (kc=0): K [64 keys][128 d] linear rows, V^T [128 d][64 pos]
  const unsigned short* kgp[4];
  const unsigned short* vgp[4];
#pragma unroll
  for (int i = 0; i < 4; ++i) {
    int c = i * 256 + tid;              // 0..1023 chunk id
    int rr = c >> 4, cc = c & 15;       // K: row rr, 16B chunk cc
    kgp[i] = Kh + base + (size_t)rr * 128 + ((cc ^ (rr & 15)) * 8);
    int d = c >> 3, c8 = c & 7;         // V: row d, chunk c8
    vgp[i] = Vtp + base + (size_t)d * 2048 + ((c8 ^ (d & 7)) * 8);
  }

  f32x16 o[4] = {};                     // o[dt]: col d = dt*32+q31, rows=q slots
  float mv = -1e30f, ls = 0.f;

  // prologue: stage tile 0 into buf 0
#pragma unroll
  for (int i = 0; i < 4; ++i) {
    int c = i * 256 + tid;
    gload_lds16(kgp[i], smem + c * 16);
    gload_lds16(vgp[i], smem + 16384 + c * 16);
  }
  __syncthreads();

  int cur = 0;
  for (int kc = 0; kc < 2048; kc += 64) {
    if (kc + 64 < 2048) {  // stage next tile into the other buffer
      char* nb = smem + ((cur ^ 1) << 15);
#pragma unroll
      for (int i = 0; i < 4; ++i) {
        int c = i * 256 + tid;
        gload_lds16(kgp[i] + (size_t)(kc + 64) * 128, nb + c * 16);
        gload_lds16(vgp[i] + (kc + 64), nb + 16384 + c * 16);
      }
    }
    const unsigned short* sK = (const unsigned short*)(smem + (cur << 15));
    const unsigned short* sV = (const unsigned short*)(smem + (cur << 15) + 16384);

    unsigned mw0 = mrow[kc >> 5] >> (4 * hi);
    unsigned mw1 = mrow[(kc >> 5) + 1] >> (4 * hi);

    // S^T: 2 key-tiles x 8 d-windows. A=K frag: row=key=q31 (lane pos), k-window wd
    f32x16 st0 = {}, st1 = {};
    __builtin_amdgcn_s_setprio(1);
#pragma unroll
    for (int wd = 0; wd < 8; ++wd) {
      int ck = ((2 * wd + hi) ^ (q31 & 15)) * 8;
      bf16x8 k0 = *(const bf16x8*)&sK[q31 * 128 + ck];
      bf16x8 k1 = *(const bf16x8*)&sK[(32 + q31) * 128 + ck];
      st0 = MFMA32(k0, qf[wd], st0);
      st1 = MFMA32(k1, qf[wd], st1);
    }
    __builtin_amdgcn_s_setprio(0);

    // mask: slot r of tile kt = key kt*32 + (r&3)+8*(r>>2)+4*hi
    float pvv[32];
#pragma unroll
    for (int r = 0; r < 16; ++r) {
      int bit = (r & 3) + 8 * (r >> 2);  // compile-time
      pvv[r] = ((mw0 >> bit) & 1u) ? st0[r] : -1e30f;
      pvv[16 + r] = ((mw1 >> bit) & 1u) ? st1[r] : -1e30f;
    }
    // max over 32 slots (tree)
    float c0 = max3f(pvv[0], pvv[1], pvv[2]);
    float c1 = max3f(pvv[3], pvv[4], pvv[5]);
    float c2 = max3f(pvv[6], pvv[7], pvv[8]);
    float c3 = max3f(pvv[9], pvv[10], pvv[11]);
    float c4 = max3f(pvv[12], pvv[13], pvv[14]);
    float c5 = max3f(pvv[15], pvv[16], pvv[17]);
    float c6 = max3f(pvv[18], pvv[19], pvv[20]);
    float c7 = max3f(pvv[21], pvv[22], pvv[23]);
    float c8 = max3f(pvv[24], pvv[25], pvv[26]);
    float c9 = max3f(pvv[27], pvv[28], pvv[29]);
    float ca = fmaxf(pvv[30], pvv[31]);
    float t0 = max3f(c0, c1, c2);
    float t1 = max3f(c3, c4, c5);
    float t2 = max3f(c6, c7, c8);
    float t3 = max3f(c9, ca, t0);
    float cmax = max3f(t1, t2, t3);
    cmax = fmaxf(cmax, __shfl_xor(cmax, 32));

    if (!__all(cmax - mv <= 11.5f)) {  // defer-max: P bounded by 2^11.5
      float mnew = fmaxf(mv, cmax);
      float fac = exp2a(mv - mnew);
      ls *= fac;
      float fr[16];
#pragma unroll
      for (int r = 0; r < 16; ++r) fr[r] = __shfl(fac, (r & 3) + 8 * (r >> 2) + 4 * hi);
#pragma unroll
      for (int dt = 0; dt < 4; ++dt)
#pragma unroll
        for (int r = 0; r < 16; ++r) o[dt][r] *= fr[r];
      mv = mnew;
    }

#pragma unroll
    for (int t = 0; t < 32; ++t) pvv[t] = exp2a(pvv[t] - mv);
    {
      float s0 = 0.f, s1 = 0.f, s2 = 0.f, s3 = 0.f;
#pragma unroll
      for (int t = 0; t < 8; ++t) {
        s0 += pvv[t]; s1 += pvv[8 + t]; s2 += pvv[16 + t]; s3 += pvv[24 + t];
      }
      ls += (s0 + s1) + (s2 + s3);
    }

    // packs: window kw covers pvv[8*kw .. 8*kw+7] (= keys kw*16 + sigma(hi,j))
    bf16x8 pa[4];
#pragma unroll
    for (int kw = 0; kw < 4; ++kw) {
      uint4v pw;
#pragma unroll
      for (int m = 0; m < 4; ++m) pw[m] = pkbf(pvv[8 * kw + 2 * m], pvv[8 * kw + 2 * m + 1]);
      pa[kw] = __builtin_bit_cast(bf16x8, pw);
    }

    // PV: o[dt] += P(window kw) x V; B-frag = sV row dt*32+q31, chunk (2kw+hi)
    __builtin_amdgcn_s_setprio(1);
#pragma unroll
    for (int dt = 0; dt < 4; ++dt) {
      int vrow = dt * 32 + q31;
#pragma unroll
      for (int kw = 0; kw < 4; ++kw) {
        int cv = ((2 * kw + hi) ^ (q31 & 7)) * 8;
        bf16x8 vf = *(const bf16x8*)&sV[vrow * 64 + cv];
        o[dt] = MFMA32(pa[kw], vf, o[dt]);
      }
    }
    __builtin_amdgcn_s_setprio(0);
    __syncthreads();
    cur ^= 1;
  }

  // normalize factors: partner lane (l^32) holds the other half of the keys
  ls += __shfl_xor(ls, 32);
  float inv = 1.f / ls;
  float ir[16];
#pragma unroll
  for (int r = 0; r < 16; ++r) ir[r] = __shfl(inv, (r & 3) + 8 * (r >> 2) + 4 * hi);

  // epilogue: two 64-row passes through sO overlay (waves 0-1, then 2-3)
  float* sO = (float*)smem;
#pragma unroll
  for (int pass = 0; pass < 2; ++pass) {
    __syncthreads();
    if ((w >> 1) == pass) {
      int wl = w & 1;
#pragma unroll
      for (int dt = 0; dt < 4; ++dt)
#pragma unroll
        for (int r = 0; r < 16; ++r) {
          int qrl = wl * 32 + (r & 3) + 8 * (r >> 2) + 4 * hi;
          sO[qrl * 132 + dt * 32 + q31] = o[dt][r] * ir[r];
        }
    }
    __syncthreads();
    {
      int row = tid >> 2, d0 = (tid & 3) * 32;
      int grow = qb + pass * 64 + row;
      unsigned short* op = O + (size_t)(b * 2048 + grow) * 2048 + h * 128 + d0;
#pragma unroll
      for (int g = 0; g < 4; ++g) {
        ushort8 pk;
#pragma unroll
        for (int e = 0; e < 8; ++e) pk[e] = f2bf(sO[row * 132 + d0 + g * 8 + e]);
        *(ushort8*)(op + g * 8) = pk;
      }
    }
  }
}

// ---------------------------------------------------------------------------
extern "C" void kernel_launch(void* const* d_in, const int* in_sizes, int n_in,
                              void* d_out, int out_size, void* d_ws, size_t ws_size,
                              hipStream_t stream) {
  const float* q      = (const float*)d_in[0];
  const float* kv     = (const float*)d_in[1];
  const float* q_pos  = (const float*)d_in[2];
  const float* kv_pos = (const float*)d_in[3];
  const int*   mask   = (const int*)d_in[4];
  const float* wq     = (const float*)d_in[5];
  const float* wk     = (const float*)d_in[6];
  const float* wv     = (const float*)d_in[7];
  const float* qls    = (const float*)d_in[8];
  const float* kls    = (const float*)d_in[9];
  const float* wo     = (const float*)d_in[10];

  char* ws = (char*)d_ws;
  const size_t SZ_ACT = (size_t)4096 * 2048 * 2;  // 16 MiB
  const size_t SZ_W   = (size_t)2048 * 2048 * 2;  // 8 MiB
  unsigned short* a_q = (unsigned short*)(ws);
  unsigned short* a_k = (unsigned short*)(ws + SZ_ACT);
  unsigned short* a_v = (unsigned short*)(ws + 2 * SZ_ACT);
  unsigned short* Qh  = (unsigned short*)(ws + 3 * SZ_ACT);
  unsigned short* Kh  = (unsigned short*)(ws + 4 * SZ_ACT);
  unsigned short* wqt = (unsigned short*)(ws + 6 * SZ_ACT);
  unsigned short* wkt = (unsigned short*)(ws + 6 * SZ_ACT + SZ_W);
  unsigned short* wvt = (unsigned short*)(ws + 6 * SZ_ACT + 2 * SZ_W);
  unsigned short* wot = (unsigned short*)(ws + 6 * SZ_ACT + 3 * SZ_W);
  unsigned*       mkb = (unsigned*)(ws + 6 * SZ_ACT + 4 * SZ_W);
  unsigned short* Ob  = a_q;  // a_q dead after Q-projection; reuse for attn out
  unsigned short* Vtr = (unsigned short*)(ws + 5 * SZ_ACT);  // V^T (direct from MODE 4)

  const size_t NEED = 6 * SZ_ACT + 4 * SZ_W + (size_t)2 * 2048 * 64 * 4;
  if (ws_size < NEED) return;  // leave d_out poisoned -> visible failure

  k_prep<<<49152, 256, 0, stream>>>((const float4v*)q, (const float4v*)q_pos,
                                    (const float4v*)kv, (const float4v*)kv_pos, mask,
                                    (ushort4v*)a_q, (ushort4v*)a_k, (ushort4v*)a_v,
                                    (unsigned long long*)mkb);
  k_tr<<<dim3(64, 64, 4), 256, 0, stream>>>(wq, wk, wv, wo, wqt, wkt, wvt, wot);

  // Q/K projections: M=4096 (32 m-tiles of 128), N=2048 (8 n-tiles of 256)
  k_gemm4<1><<<dim3(8, 32), 256, 0, stream>>>(a_q, wqt, Qh, qls);
  k_gemm4<2><<<dim3(8, 32), 256, 0, stream>>>(a_k, wkt, Kh, kls);
  // V^T directly: A=wvt (M=2048=(h,d), 16 m-tiles), Bt=a_v (N=4096, 16 n-tiles)
  k_gemm4<4><<<dim3(16, 16), 256, 0, stream>>>(wvt, a_v, Vtr, nullptr);

  k_attn<<<dim3(16, 32), 256, 0, stream>>>(Qh, Kh, Vtr, mkb, Ob);

  // out-proj: M=4096, N=2048 -> fp32 d_out
  k_gemm4<3><<<dim3(8, 32), 256, 0, stream>>>(Ob, wot, d_out, nullptr);
}

// Round 15
// 314.442 us; speedup vs baseline: 1.4577x; 1.4577x over previous
//
#include <hip/hip_runtime.h>
#include <hip/hip_bf16.h>

// ---------------------------------------------------------------------------
// AttentionBlock: qkv-proj (+LN on q,k) -> masked flash attention -> out-proj
// B=2, S=2048, E=2048, H=16, D=128.
// GEMMs: tri-buffered counted-vmcnt pipeline (256x128 tile, BK=64, 8 waves,
// 3 LDS buffers, vmcnt(12) mid-loop: t+1 AND t+2 stay in flight) +
// XCD-clustered block remap (A-panel L2 residency).
// Attention: bf16 MFMA 32x32x16, swapped QK^T, exp2-domain softmax, dbuf,
// XCD-clustered (K/V working set 4MB = L2 per XCD).
// V^T produced directly by swapped-operand GEMM (MODE 4, key-perm store).
// ---------------------------------------------------------------------------

typedef __attribute__((ext_vector_type(8))) __bf16 bf16x8;
typedef __attribute__((ext_vector_type(4))) float f32x4;
typedef __attribute__((ext_vector_type(16))) float f32x16;
typedef __attribute__((ext_vector_type(8))) unsigned short ushort8;
typedef __attribute__((ext_vector_type(4))) unsigned short ushort4v;
typedef __attribute__((ext_vector_type(4))) unsigned uint4v;
typedef __attribute__((ext_vector_type(4))) float float4v;

#define MFMA16(a, b, c) __builtin_amdgcn_mfma_f32_16x16x32_bf16((a), (b), (c), 0, 0, 0)
#define MFMA32(a, b, c) __builtin_amdgcn_mfma_f32_32x32x16_bf16((a), (b), (c), 0, 0, 0)

__device__ __forceinline__ unsigned short f2bf(float f) {
  unsigned u = __builtin_bit_cast(unsigned, f);
  u += 0x7fffu + ((u >> 16) & 1u);           // RNE
  return (unsigned short)(u >> 16);
}

__device__ __forceinline__ unsigned pkbf(float lo, float hi) {  // bf16(lo)|bf16(hi)<<16
  unsigned d;
  asm("v_cvt_pk_bf16_f32 %0, %1, %2" : "=v"(d) : "v"(lo), "v"(hi));
  return d;
}

__device__ __forceinline__ float max3f(float a, float b, float c) {
  float d;
  asm("v_max3_f32 %0, %1, %2, %3" : "=v"(d) : "v"(a), "v"(b), "v"(c));
  return d;
}

__device__ __forceinline__ float exp2a(float x) {  // 2^x
  float d;
  asm("v_exp_f32 %0, %1" : "=v"(d) : "v"(x));
  return d;
}

__device__ __forceinline__ void gload_lds16(const void* g, void* l) {
  __builtin_amdgcn_global_load_lds(
      (const __attribute__((address_space(1))) void*)g,
      (__attribute__((address_space(3))) void*)l, 16, 0, 0);
}

// ---------------- prep (fused): adds/cvt, mask bitmask, weight transpose ---
// blocks [0,8192): q-path; [8192,16384): kv-path; [16384,49152): mask;
// [49152,65536): fp32[K][N] -> bf16[N][K] transpose of the 4 weights.
__global__ __launch_bounds__(256) void k_prep(const float4v* __restrict__ q,
                                              const float4v* __restrict__ q_pos,
                                              const float4v* __restrict__ kv,
                                              const float4v* __restrict__ kv_pos,
                                              const int* __restrict__ mask,
                                              ushort4v* __restrict__ a_q,
                                              ushort4v* __restrict__ a_k,
                                              ushort4v* __restrict__ a_v,
                                              unsigned long long* __restrict__ mkb,
                                              const float* __restrict__ s0, const float* __restrict__ s1,
                                              const float* __restrict__ s2, const float* __restrict__ s3,
                                              unsigned short* __restrict__ d0, unsigned short* __restrict__ d1,
                                              unsigned short* __restrict__ d2, unsigned short* __restrict__ d3) {
  __shared__ float t[32][33];
  int bx = blockIdx.x, tid = threadIdx.x;
  if (bx < 8192) {
    int i = bx * 256 + tid;
    float4v a = q[i] + q_pos[i];
    ushort4v r;
    r[0] = f2bf(a[0]); r[1] = f2bf(a[1]); r[2] = f2bf(a[2]); r[3] = f2bf(a[3]);
    a_q[i] = r;
  } else if (bx < 16384) {
    int i = (bx - 8192) * 256 + tid;
    float4v a = kv[i];
    float4v s = a + kv_pos[i];
    ushort4v ra, rb;
    ra[0] = f2bf(s[0]); ra[1] = f2bf(s[1]); ra[2] = f2bf(s[2]); ra[3] = f2bf(s[3]);
    rb[0] = f2bf(a[0]); rb[1] = f2bf(a[1]); rb[2] = f2bf(a[2]); rb[3] = f2bf(a[3]);
    a_k[i] = ra; a_v[i] = rb;
  } else if (bx < 49152) {
    int i = (bx - 16384) * 256 + tid;
    unsigned long long b = __ballot(mask[i] != 0);
    if ((tid & 63) == 0) mkb[i >> 6] = b;
  } else {
    int idx = bx - 49152;
    int z = idx >> 12, rem = idx & 4095;
    int r0 = (rem >> 6) * 32, c0 = (rem & 63) * 32;
    const float* S; unsigned short* D;
    switch (z) {
      case 0: S = s0; D = d0; break;
      case 1: S = s1; D = d1; break;
      case 2: S = s2; D = d2; break;
      default: S = s3; D = d3; break;
    }
    int x = tid & 31, y = tid >> 5;
#pragma unroll
    for (int i = 0; i < 4; ++i) t[y + 8 * i][x] = S[(size_t)(r0 + y + 8 * i) * 2048 + c0 + x];
    __syncthreads();
#pragma unroll
    for (int i = 0; i < 4; ++i)
      D[(size_t)(c0 + y + 8 * i) * 2048 + r0 + x] = f2bf(t[x][y + 8 * i]);
  }
}

// ---------------- GEMM: 256x128 tile, BK=64, 8 waves, tri-buffer -----------
// Counted-vmcnt pipeline (FIXED counts): at iter t, stage(t+2) then vmcnt(12)
// -> tiles t+1 AND t+2 stay in flight across the barrier; tile t guaranteed
// (drained at iter t-1). Tail: vmcnt(6) at NT-2, vmcnt(0) at NT-1.
// MODE 1: LN*scale*rsqrt(D)*log2e (Q) -> [B,H,S,D] bf16
// MODE 2: LN*scale (K)               -> [B,H,S,D] bf16
// MODE 3: fp32 direct to [M][2048] (final out-proj)
// MODE 4: V^T direct: A=wvt (M=2048=(h,d)), Bt=a_v (N=4096=(b,s));
//         store at Vtp[bh][d][(s&~15)|swap23(s&15)] bf16.
template <int MODE>
__global__ __launch_bounds__(512, 2) void k_gemm8(const unsigned short* __restrict__ A,
                                                  const unsigned short* __restrict__ Bt,
                                                  void* __restrict__ Cv,
                                                  const float* __restrict__ lnsc) {
  constexpr int K = 2048;
  constexpr int NT = 32;                 // K / 64
  constexpr int BUF = 49152;             // A 32KB + B 16KB per K-tile
  __shared__ __attribute__((aligned(16))) char smem[3 * BUF];  // 144 KB
  int tid = threadIdx.x;
  int lane = tid & 63, w = tid >> 6;
  int wr = w >> 2, wc = w & 3;           // 2 x 4 wave grid
  int r15 = lane & 15, blk = lane >> 4;
  // XCD-clustered remap (bijective for grid==256): same-A blocks share an XCD
  int L = blockIdx.y * gridDim.x + blockIdx.x;
  int xcd = L & 7, slot = L >> 3;        // slot 0..31
  int mt, nt;
  if constexpr (MODE == 4) { mt = xcd; nt = slot; }          // M=2048: 8 m-tiles
  else { mt = xcd * 2 + (slot >> 4); nt = slot & 15; }       // M=4096: 16 m-tiles
  int n0 = nt * 128, m0 = mt * 256;
  const unsigned short* Abase = A + (size_t)m0 * K;
  const unsigned short* Bbase = Bt + (size_t)n0 * K;
  f32x4 acc[8][2] = {};

  // per-thread staging descriptors (source XOR-pre-swizzled, dest linear)
  const unsigned short* ag[4]; int al[4];
  const unsigned short* bg[2]; int bl[2];
#pragma unroll
  for (int i = 0; i < 4; ++i) {
    int c = i * 512 + tid;               // 0..2047: A rows 0..255, 8 chunks/row
    int row = c >> 3, cc = c & 7;
    ag[i] = Abase + (size_t)row * K + ((cc ^ (row & 7)) * 8);
    al[i] = c * 16;
  }
#pragma unroll
  for (int i = 0; i < 2; ++i) {
    int c = i * 512 + tid;               // 0..1023: B rows 0..127
    int row = c >> 3, cc = c & 7;
    bg[i] = Bbase + (size_t)row * K + ((cc ^ (row & 7)) * 8);
    bl[i] = 32768 + c * 16;
  }

  auto stage = [&](int t) {
    char* buf = smem + (t % 3) * BUF;
    int kt = t * 64;
#pragma unroll
    for (int i = 0; i < 4; ++i) gload_lds16(ag[i] + kt, buf + al[i]);
#pragma unroll
    for (int i = 0; i < 2; ++i) gload_lds16(bg[i] + kt, buf + bl[i]);
  };

  stage(0);
  stage(1);

  for (int t = 0; t < NT; ++t) {
    if (t + 2 < NT) {
      stage(t + 2);                                      // 6 loads into buf[(t+2)%3]
      asm volatile("s_waitcnt vmcnt(12)" ::: "memory");  // t+1,t+2 in flight; t landed
    } else if (t + 1 < NT) {
      asm volatile("s_waitcnt vmcnt(6)" ::: "memory");   // t landed; t+1 in flight
    } else {
      asm volatile("s_waitcnt vmcnt(0)" ::: "memory");   // tail drain
    }
    __builtin_amdgcn_s_barrier();        // B1: all waves' tile-t loads drained
    __builtin_amdgcn_sched_barrier(0);
    const unsigned short* sA = (const unsigned short*)(smem + (t % 3) * BUF);
    const unsigned short* sB = (const unsigned short*)(smem + (t % 3) * BUF + 32768);
#pragma unroll
    for (int kk = 0; kk < 2; ++kk) {
      bf16x8 av[8], bv[2];
#pragma unroll
      for (int i = 0; i < 8; ++i) {
        int row = wr * 128 + i * 16 + r15;
        av[i] = *(const bf16x8*)&sA[row * 64 + (((kk * 4 + blk) ^ (row & 7)) * 8)];
      }
#pragma unroll
      for (int j = 0; j < 2; ++j) {
        int row = wc * 32 + j * 16 + r15;
        bv[j] = *(const bf16x8*)&sB[row * 64 + (((kk * 4 + blk) ^ (row & 7)) * 8)];
      }
#pragma unroll
      for (int i = 0; i < 8; ++i)
#pragma unroll
        for (int j = 0; j < 2; ++j) acc[i][j] = MFMA16(av[i], bv[j], acc[i][j]);
    }
    asm volatile("s_waitcnt lgkmcnt(0)" ::: "memory");  // my LDS reads done
    __builtin_amdgcn_s_barrier();        // B2: buf[t%3] safe to overwrite next iter
  }
  __syncthreads();                        // full fence before LDS reuse in epilogue

  if constexpr (MODE == 3) {
    float* C = (float*)Cv;
#pragma unroll
    for (int i = 0; i < 8; ++i)
#pragma unroll
      for (int r = 0; r < 4; ++r) {
        int rowl = wr * 128 + i * 16 + blk * 4 + r;   // C row=(lane>>4)*4+reg
#pragma unroll
        for (int j = 0; j < 2; ++j) {
          int coll = wc * 32 + j * 16 + r15;          // C col=lane&15
          C[(size_t)(m0 + rowl) * 2048 + n0 + coll] = acc[i][j][r];
        }
      }
  } else if constexpr (MODE == 4) {
    // V^T: rowg=(h,d), col=(b,s); key s stored at pos (s&~15)|swap23(r15)
    unsigned short* Vtp = (unsigned short*)Cv;
    int p15 = (r15 & 3) | ((r15 & 4) << 1) | ((r15 & 8) >> 1);
#pragma unroll
    for (int i = 0; i < 8; ++i)
#pragma unroll
      for (int r = 0; r < 4; ++r) {
        int rowg = m0 + wr * 128 + i * 16 + blk * 4 + r;  // (h,d)
        int h = rowg >> 7, d = rowg & 127;
#pragma unroll
        for (int j = 0; j < 2; ++j) {
          int col = n0 + wc * 32 + j * 16;                // (b, s&~15)
          int b = col >> 11, s16 = col & 2047;
          Vtp[(((size_t)(b * 16 + h) * 128 + d) * 2048) + s16 + p15] = f2bf(acc[i][j][r]);
        }
      }
  } else {
    // MODE 1/2: LayerNorm over the 128-col tile (= head_dim); head = nt
    float* sSum = (float*)smem;            // [4][256]
    float* sSq  = (float*)smem + 1024;     // [4][256]
#pragma unroll
    for (int i = 0; i < 8; ++i)
#pragma unroll
      for (int r = 0; r < 4; ++r) {
        float v0 = acc[i][0][r], v1 = acc[i][1][r];
        float sm = v0 + v1, sq = v0 * v0 + v1 * v1;
        sm += __shfl_xor(sm, 1); sq += __shfl_xor(sq, 1);
        sm += __shfl_xor(sm, 2); sq += __shfl_xor(sq, 2);
        sm += __shfl_xor(sm, 4); sq += __shfl_xor(sq, 4);
        sm += __shfl_xor(sm, 8); sq += __shfl_xor(sq, 8);
        if (r15 == 0) {
          int rowl = wr * 128 + i * 16 + blk * 4 + r;
          sSum[wc * 256 + rowl] = sm;
          sSq[wc * 256 + rowl] = sq;
        }
      }
    __syncthreads();
    unsigned short* Hout = (unsigned short*)Cv;
    int h = nt;
#pragma unroll
    for (int i = 0; i < 8; ++i)
#pragma unroll
      for (int r = 0; r < 4; ++r) {
        int rowl = wr * 128 + i * 16 + blk * 4 + r;
        float sm = (sSum[rowl] + sSum[256 + rowl]) + (sSum[512 + rowl] + sSum[768 + rowl]);
        float sq = (sSq[rowl] + sSq[256 + rowl]) + (sSq[512 + rowl] + sSq[768 + rowl]);
        float mean = sm * 0.0078125f;
        float var = sq * 0.0078125f - mean * mean;
        float rstd = rsqrtf(var + 1e-6f);
        int rowg = m0 + rowl;
        int b = rowg >> 11, s = rowg & 2047;
        unsigned short* orow = Hout + (((size_t)b * 16 + h) * 2048 + s) * 128;
#pragma unroll
        for (int j = 0; j < 2; ++j) {
          int d = wc * 32 + j * 16 + r15;
          float v = acc[i][j][r];
          // log2e folded in for Q: attention softmax runs in exp2 domain
          if constexpr (MODE == 1)
            v = (v - mean) * rstd * lnsc[d] * (0.08838834764831845f * 1.4426950408889634f);
          else
            v = (v - mean) * rstd * lnsc[d];
          orow[d] = f2bf(v);
        }
      }
  }
}

// ---------------- flash attention: 32x32x16 MFMA, XCD-clustered ------------
// 4 waves x 32 q = QBLK 128; KVBLK=64; dbuf 64 KB; grid 512 -> 2 blocks/CU.
// XCD k owns bh {4k..4k+3} (K/V working set 4MB = L2 per XCD).
// S^T = mfma32(K, Q): D col=lane&31=q, slot r -> key (r&3)+8*(r>>2)+4*hi.
// P packs feed PV A-frag in natural order (V^T carries the key-perm, MODE 4).
__global__ __launch_bounds__(256, 2) void k_attn(const unsigned short* __restrict__ Qh,
                                                 const unsigned short* __restrict__ Kh,
                                                 const unsigned short* __restrict__ Vtp,
                                                 const unsigned* __restrict__ maskb,
                                                 unsigned short* __restrict__ O) {
  __shared__ __attribute__((aligned(16))) char smem[65536];  // 2 x (sK 16K + sV 16K)
  int tid = threadIdx.x, w = tid >> 6;
  int lane = tid & 63;
  int q31 = lane & 31, hi = lane >> 5;
  // XCD-clustered remap (bijective: grid = 16 x 32 = 512)
  int L = blockIdx.y * 16 + blockIdx.x;
  int xcd = L & 7, slot = L >> 3;        // slot 0..63
  int bh = xcd * 4 + (slot >> 4);
  int qb = (slot & 15) * 128;
  int b = bh >> 4, h = bh & 15;
  size_t base = (size_t)bh * (2048 * 128);
  int qrow = qb + w * 32 + q31;

  bf16x8 qf[8];  // Q (B-operand): col=q31, k-window wd: d = wd*16 + hi*8 + j
  {
    const unsigned short* qp = Qh + base + (size_t)qrow * 128 + hi * 8;
#pragma unroll
    for (int wd = 0; wd < 8; ++wd) qf[wd] = *(const bf16x8*)(qp + wd * 16);
  }
  const unsigned* mrow = maskb + ((size_t)b * 2048 + qrow) * 64;

  // staging bases (kc=0): K [64 keys][128 d] linear rows, V^T [128 d][64 pos]
  const unsigned short* kgp[4];
  const unsigned short* vgp[4];
#pragma unroll
  for (int i = 0; i < 4; ++i) {
    int c = i * 256 + tid;              // 0..1023 chunk id
    int rr = c >> 4, cc = c & 15;       // K: row rr, 16B chunk cc
    kgp[i] = Kh + base + (size_t)rr * 128 + ((cc ^ (rr & 15)) * 8);
    int d = c >> 3, c8 = c & 7;         // V: row d, chunk c8
    vgp[i] = Vtp + base + (size_t)d * 2048 + ((c8 ^ (d & 7)) * 8);
  }

  f32x16 o[4] = {};                     // o[dt]: col d = dt*32+q31, rows=q slots
  float mv = -1e30f, ls = 0.f;

  // prologue: stage tile 0 into buf 0
#pragma unroll
  for (int i = 0; i < 4; ++i) {
    int c = i * 256 + tid;
    gload_lds16(kgp[i], smem + c * 16);
    gload_lds16(vgp[i], smem + 16384 + c * 16);
  }
  __syncthreads();

  int cur = 0;
  for (int kc = 0; kc < 2048; kc += 64) {
    if (kc + 64 < 2048) {  // stage next tile into the other buffer
      char* nb = smem + ((cur ^ 1) << 15);
#pragma unroll
      for (int i = 0; i < 4; ++i) {
        int c = i * 256 + tid;
        gload_lds16(kgp[i] + (size_t)(kc + 64) * 128, nb + c * 16);
        gload_lds16(vgp[i] + (kc + 64), nb + 16384 + c * 16);
      }
    }
    const unsigned short* sK = (const unsigned short*)(smem + (cur << 15));
    const unsigned short* sV = (const unsigned short*)(smem + (cur << 15) + 16384);

    unsigned mw0 = mrow[kc >> 5] >> (4 * hi);
    unsigned mw1 = mrow[(kc >> 5) + 1] >> (4 * hi);

    // S^T: 2 key-tiles x 8 d-windows. A=K frag: row=key=q31 (lane pos), k-window wd
    f32x16 st0 = {}, st1 = {};
    __builtin_amdgcn_s_setprio(1);
#pragma unroll
    for (int wd = 0; wd < 8; ++wd) {
      int ck = ((2 * wd + hi) ^ (q31 & 15)) * 8;
      bf16x8 k0 = *(const bf16x8*)&sK[q31 * 128 + ck];
      bf16x8 k1 = *(const bf16x8*)&sK[(32 + q31) * 128 + ck];
      st0 = MFMA32(k0, qf[wd], st0);
      st1 = MFMA32(k1, qf[wd], st1);
    }
    __builtin_amdgcn_s_setprio(0);

    // mask: slot r of tile kt = key kt*32 + (r&3)+8*(r>>2)+4*hi
    float pvv[32];
#pragma unroll
    for (int r = 0; r < 16; ++r) {
      int bit = (r & 3) + 8 * (r >> 2);  // compile-time
      pvv[r] = ((mw0 >> bit) & 1u) ? st0[r] : -1e30f;
      pvv[16 + r] = ((mw1 >> bit) & 1u) ? st1[r] : -1e30f;
    }
    // max over 32 slots (tree)
    float c0 = max3f(pvv[0], pvv[1], pvv[2]);
    float c1 = max3f(pvv[3], pvv[4], pvv[5]);
    float c2 = max3f(pvv[6], pvv[7], pvv[8]);
    float c3 = max3f(pvv[9], pvv[10], pvv[11]);
    float c4 = max3f(pvv[12], pvv[13], pvv[14]);
    float c5 = max3f(pvv[15], pvv[16], pvv[17]);
    float c6 = max3f(pvv[18], pvv[19], pvv[20]);
    float c7 = max3f(pvv[21], pvv[22], pvv[23]);
    float c8 = max3f(pvv[24], pvv[25], pvv[26]);
    float c9 = max3f(pvv[27], pvv[28], pvv[29]);
    float ca = fmaxf(pvv[30], pvv[31]);
    float t0 = max3f(c0, c1, c2);
    float t1 = max3f(c3, c4, c5);
    float t2 = max3f(c6, c7, c8);
    float t3 = max3f(c9, ca, t0);
    float cmax = max3f(t1, t2, t3);
    cmax = fmaxf(cmax, __shfl_xor(cmax, 32));

    if (!__all(cmax - mv <= 11.5f)) {  // defer-max: P bounded by 2^11.5
      float mnew = fmaxf(mv, cmax);
      float fac = exp2a(mv - mnew);
      ls *= fac;
      float fr[16];
#pragma unroll
      for (int r = 0; r < 16; ++r) fr[r] = __shfl(fac, (r & 3) + 8 * (r >> 2) + 4 * hi);
#pragma unroll
      for (int dt = 0; dt < 4; ++dt)
#pragma unroll
        for (int r = 0; r < 16; ++r) o[dt][r] *= fr[r];
      mv = mnew;
    }

#pragma unroll
    for (int t = 0; t < 32; ++t) pvv[t] = exp2a(pvv[t] - mv);
    {
      float s0 = 0.f, s1 = 0.f, s2 = 0.f, s3 = 0.f;
#pragma unroll
      for (int t = 0; t < 8; ++t) {
        s0 += pvv[t]; s1 += pvv[8 + t]; s2 += pvv[16 + t]; s3 += pvv[24 + t];
      }
      ls += (s0 + s1) + (s2 + s3);
    }

    // packs: window kw covers pvv[8*kw .. 8*kw+7] (= keys kw*16 + sigma(hi,j))
    bf16x8 pa[4];
#pragma unroll
    for (int kw = 0; kw < 4; ++kw) {
      uint4v pw;
#pragma unroll
      for (int m = 0; m < 4; ++m) pw[m] = pkbf(pvv[8 * kw + 2 * m], pvv[8 * kw + 2 * m + 1]);
      pa[kw] = __builtin_bit_cast(bf16x8, pw);
    }

    // PV: o[dt] += P(window kw) x V; B-frag = sV row dt*32+q31, chunk (2kw+hi)
    __builtin_amdgcn_s_setprio(1);
#pragma unroll
    for (int dt = 0; dt < 4; ++dt) {
      int vrow = dt * 32 + q31;
#pragma unroll
      for (int kw = 0; kw < 4; ++kw) {
        int cv = ((2 * kw + hi) ^ (q31 & 7)) * 8;
        bf16x8 vf = *(const bf16x8*)&sV[vrow * 64 + cv];
        o[dt] = MFMA32(pa[kw], vf, o[dt]);
      }
    }
    __builtin_amdgcn_s_setprio(0);
    __syncthreads();
    cur ^= 1;
  }

  // normalize factors: partner lane (l^32) holds the other half of the keys
  ls += __shfl_xor(ls, 32);
  float inv = 1.f / ls;
  float ir[16];
#pragma unroll
  for (int r = 0; r < 16; ++r) ir[r] = __shfl(inv, (r & 3) + 8 * (r >> 2) + 4 * hi);

  // epilogue: two 64-row passes through sO overlay (waves 0-1, then 2-3)
  float* sO = (float*)smem;
#pragma unroll
  for (int pass = 0; pass < 2; ++pass) {
    __syncthreads();
    if ((w >> 1) == pass) {
      int wl = w & 1;
#pragma unroll
      for (int dt = 0; dt < 4; ++dt)
#pragma unroll
        for (int r = 0; r < 16; ++r) {
          int qrl = wl * 32 + (r & 3) + 8 * (r >> 2) + 4 * hi;
          sO[qrl * 132 + dt * 32 + q31] = o[dt][r] * ir[r];
        }
    }
    __syncthreads();
    {
      int row = tid >> 2, d0 = (tid & 3) * 32;
      int grow = qb + pass * 64 + row;
      unsigned short* op = O + (size_t)(b * 2048 + grow) * 2048 + h * 128 + d0;
#pragma unroll
      for (int g = 0; g < 4; ++g) {
        ushort8 pk;
#pragma unroll
        for (int e = 0; e < 8; ++e) pk[e] = f2bf(sO[row * 132 + d0 + g * 8 + e]);
        *(ushort8*)(op + g * 8) = pk;
      }
    }
  }
}

// ---------------------------------------------------------------------------
extern "C" void kernel_launch(void* const* d_in, const int* in_sizes, int n_in,
                              void* d_out, int out_size, void* d_ws, size_t ws_size,
                              hipStream_t stream) {
  const float* q      = (const float*)d_in[0];
  const float* kv     = (const float*)d_in[1];
  const float* q_pos  = (const float*)d_in[2];
  const float* kv_pos = (const float*)d_in[3];
  const int*   mask   = (const int*)d_in[4];
  const float* wq     = (const float*)d_in[5];
  const float* wk     = (const float*)d_in[6];
  const float* wv     = (const float*)d_in[7];
  const float* qls    = (const float*)d_in[8];
  const float* kls    = (const float*)d_in[9];
  const float* wo     = (const float*)d_in[10];

  char* ws = (char*)d_ws;
  const size_t SZ_ACT = (size_t)4096 * 2048 * 2;  // 16 MiB
  const size_t SZ_W   = (size_t)2048 * 2048 * 2;  // 8 MiB
  unsigned short* a_q = (unsigned short*)(ws);
  unsigned short* a_k = (unsigned short*)(ws + SZ_ACT);
  unsigned short* a_v = (unsigned short*)(ws + 2 * SZ_ACT);
  unsigned short* Qh  = (unsigned short*)(ws + 3 * SZ_ACT);
  unsigned short* Kh  = (unsigned short*)(ws + 4 * SZ_ACT);
  unsigned short* wqt = (unsigned short*)(ws + 6 * SZ_ACT);
  unsigned short* wkt = (unsigned short*)(ws + 6 * SZ_ACT + SZ_W);
  unsigned short* wvt = (unsigned short*)(ws + 6 * SZ_ACT + 2 * SZ_W);
  unsigned short* wot = (unsigned short*)(ws + 6 * SZ_ACT + 3 * SZ_W);
  unsigned*       mkb = (unsigned*)(ws + 6 * SZ_ACT + 4 * SZ_W);
  unsigned short* Ob  = a_q;  // a_q dead after Q-projection; reuse for attn out
  unsigned short* Vtr = (unsigned short*)(ws + 5 * SZ_ACT);  // V^T (direct from MODE 4)

  const size_t NEED = 6 * SZ_ACT + 4 * SZ_W + (size_t)2 * 2048 * 64 * 4;
  if (ws_size < NEED) return;  // leave d_out poisoned -> visible failure

  k_prep<<<65536, 256, 0, stream>>>((const float4v*)q, (const float4v*)q_pos,
                                    (const float4v*)kv, (const float4v*)kv_pos, mask,
                                    (ushort4v*)a_q, (ushort4v*)a_k, (ushort4v*)a_v,
                                    (unsigned long long*)mkb,
                                    wq, wk, wv, wo, wqt, wkt, wvt, wot);

  // Q/K projections: M=4096 (16 m-blocks), N=2048 (16 head-blocks) = 256 blocks
  k_gemm8<1><<<dim3(16, 16), 512, 0, stream>>>(a_q, wqt, Qh, qls);
  k_gemm8<2><<<dim3(16, 16), 512, 0, stream>>>(a_k, wkt, Kh, kls);
  // V^T directly: A=wvt (M=2048=(h,d), 8 m-blocks), Bt=a_v (N=4096, 32 n-blocks)
  k_gemm8<4><<<dim3(32, 8), 512, 0, stream>>>(wvt, a_v, Vtr, nullptr);

  k_attn<<<dim3(16, 32), 256, 0, stream>>>(Qh, Kh, Vtr, mkb, Ob);

  // out-proj: M=4096, N=2048 -> fp32 d_out
  k_gemm8<3><<<dim3(16, 16), 512, 0, stream>>>(Ob, wot, d_out, nullptr);
}

// Round 16
// 306.992 us; speedup vs baseline: 1.4931x; 1.0243x over previous
//
#include <hip/hip_runtime.h>
#include <hip/hip_bf16.h>

// ---------------------------------------------------------------------------
// AttentionBlock: qkv-proj (+LN on q,k) -> masked flash attention -> out-proj
// B=2, S=2048, E=2048, H=16, D=128.
// Projections: ONE merged 768-block launch (Q | K | V^T), each a 256x128-tile
// BK=64 8-wave tri-buffered counted-vmcnt GEMM, XCD-clustered.
// Attention: bf16 MFMA 32x32x16, swapped QK^T, exp2-domain softmax, dbuf,
// XCD-clustered (K/V working set 4MB = L2 per XCD). No setprio (lockstep).
// V^T produced directly by swapped-operand GEMM (key-perm store).
// ---------------------------------------------------------------------------

typedef __attribute__((ext_vector_type(8))) __bf16 bf16x8;
typedef __attribute__((ext_vector_type(4))) float f32x4;
typedef __attribute__((ext_vector_type(16))) float f32x16;
typedef __attribute__((ext_vector_type(8))) unsigned short ushort8;
typedef __attribute__((ext_vector_type(4))) unsigned short ushort4v;
typedef __attribute__((ext_vector_type(4))) unsigned uint4v;
typedef __attribute__((ext_vector_type(4))) float float4v;

#define MFMA16(a, b, c) __builtin_amdgcn_mfma_f32_16x16x32_bf16((a), (b), (c), 0, 0, 0)
#define MFMA32(a, b, c) __builtin_amdgcn_mfma_f32_32x32x16_bf16((a), (b), (c), 0, 0, 0)

__device__ __forceinline__ unsigned short f2bf(float f) {
  unsigned u = __builtin_bit_cast(unsigned, f);
  u += 0x7fffu + ((u >> 16) & 1u);           // RNE
  return (unsigned short)(u >> 16);
}

__device__ __forceinline__ unsigned pkbf(float lo, float hi) {  // bf16(lo)|bf16(hi)<<16
  unsigned d;
  asm("v_cvt_pk_bf16_f32 %0, %1, %2" : "=v"(d) : "v"(lo), "v"(hi));
  return d;
}

__device__ __forceinline__ float max3f(float a, float b, float c) {
  float d;
  asm("v_max3_f32 %0, %1, %2, %3" : "=v"(d) : "v"(a), "v"(b), "v"(c));
  return d;
}

__device__ __forceinline__ float exp2a(float x) {  // 2^x
  float d;
  asm("v_exp_f32 %0, %1" : "=v"(d) : "v"(x));
  return d;
}

__device__ __forceinline__ void gload_lds16(const void* g, void* l) {
  __builtin_amdgcn_global_load_lds(
      (const __attribute__((address_space(1))) void*)g,
      (__attribute__((address_space(3))) void*)l, 16, 0, 0);
}

// ---------------- prep (fused, grid-stride): cvt, mask, weight transpose ---
// blocks [0,4096): q-path x2; [4096,8192): kv-path x2; [8192,16384): mask x4;
// [16384,32768): fp32[K][N] -> bf16[N][K] transpose of the 4 weights.
__global__ __launch_bounds__(256) void k_prep(const float4v* __restrict__ q,
                                              const float4v* __restrict__ q_pos,
                                              const float4v* __restrict__ kv,
                                              const float4v* __restrict__ kv_pos,
                                              const int* __restrict__ mask,
                                              ushort4v* __restrict__ a_q,
                                              ushort4v* __restrict__ a_k,
                                              ushort4v* __restrict__ a_v,
                                              unsigned long long* __restrict__ mkb,
                                              const float* __restrict__ s0, const float* __restrict__ s1,
                                              const float* __restrict__ s2, const float* __restrict__ s3,
                                              unsigned short* __restrict__ d0, unsigned short* __restrict__ d1,
                                              unsigned short* __restrict__ d2, unsigned short* __restrict__ d3) {
  __shared__ float t[32][33];
  int bx = blockIdx.x, tid = threadIdx.x;
  if (bx < 4096) {
#pragma unroll
    for (int k = 0; k < 2; ++k) {
      int i = bx * 256 + tid + k * 1048576;
      float4v a = q[i] + q_pos[i];
      ushort4v r;
      r[0] = f2bf(a[0]); r[1] = f2bf(a[1]); r[2] = f2bf(a[2]); r[3] = f2bf(a[3]);
      a_q[i] = r;
    }
  } else if (bx < 8192) {
#pragma unroll
    for (int k = 0; k < 2; ++k) {
      int i = (bx - 4096) * 256 + tid + k * 1048576;
      float4v a = kv[i];
      float4v s = a + kv_pos[i];
      ushort4v ra, rb;
      ra[0] = f2bf(s[0]); ra[1] = f2bf(s[1]); ra[2] = f2bf(s[2]); ra[3] = f2bf(s[3]);
      rb[0] = f2bf(a[0]); rb[1] = f2bf(a[1]); rb[2] = f2bf(a[2]); rb[3] = f2bf(a[3]);
      a_k[i] = ra; a_v[i] = rb;
    }
  } else if (bx < 16384) {
#pragma unroll
    for (int k = 0; k < 4; ++k) {
      int i = (bx - 8192) * 256 + tid + k * 2097152;
      unsigned long long b = __ballot(mask[i] != 0);
      if ((tid & 63) == 0) mkb[i >> 6] = b;
    }
  } else {
    int idx = bx - 16384;
    int z = idx >> 12, rem = idx & 4095;
    int r0 = (rem >> 6) * 32, c0 = (rem & 63) * 32;
    const float* S; unsigned short* D;
    switch (z) {
      case 0: S = s0; D = d0; break;
      case 1: S = s1; D = d1; break;
      case 2: S = s2; D = d2; break;
      default: S = s3; D = d3; break;
    }
    int x = tid & 31, y = tid >> 5;
#pragma unroll
    for (int i = 0; i < 4; ++i) t[y + 8 * i][x] = S[(size_t)(r0 + y + 8 * i) * 2048 + c0 + x];
    __syncthreads();
#pragma unroll
    for (int i = 0; i < 4; ++i)
      D[(size_t)(c0 + y + 8 * i) * 2048 + r0 + x] = f2bf(t[x][y + 8 * i]);
  }
}

// ---------------- merged QKV projection GEMM (768 blocks) ------------------
// mode 0: Q = a_q x wqt, LN*scale*rsqrt(D)*log2e -> Qh [B,H,S,D] bf16
// mode 1: K = a_k x wkt, LN*scale               -> Kh [B,H,S,D] bf16
// mode 2: V^T = wvt x a_v, key-perm store       -> Vtp [bh][d][pos] bf16
// Body: 256x128 tile, BK=64, 8 waves, tri-buffer, counted vmcnt(12).
__global__ __launch_bounds__(512, 2) void k_qkv(const unsigned short* __restrict__ a_q,
                                                const unsigned short* __restrict__ wqt,
                                                unsigned short* __restrict__ Qh,
                                                const float* __restrict__ qls,
                                                const unsigned short* __restrict__ a_k,
                                                const unsigned short* __restrict__ wkt,
                                                unsigned short* __restrict__ Kh,
                                                const float* __restrict__ kls,
                                                const unsigned short* __restrict__ wvt,
                                                const unsigned short* __restrict__ a_v,
                                                unsigned short* __restrict__ Vtp) {
  constexpr int K = 2048;
  constexpr int NT = 32;                 // K / 64
  constexpr int BUF = 49152;             // A 32KB + B 16KB per K-tile
  __shared__ __attribute__((aligned(16))) char smem[3 * BUF];  // 144 KB
  int tid = threadIdx.x;
  int lane = tid & 63, w = tid >> 6;
  int wr = w >> 2, wc = w & 3;           // 2 x 4 wave grid
  int r15 = lane & 15, blk = lane >> 4;
  int mode = blockIdx.x >> 8;            // 0:Q 1:K 2:V
  int L = blockIdx.x & 255;
  int xcd = L & 7, slot = L >> 3;        // slot 0..31
  int mt, nt;
  if (mode == 2) { mt = xcd; nt = slot; }                    // M=2048: 8 m-tiles
  else { mt = xcd * 2 + (slot >> 4); nt = slot & 15; }       // M=4096: 16 m-tiles
  int n0 = nt * 128, m0 = mt * 256;
  const unsigned short* A = (mode == 0) ? a_q : (mode == 1) ? a_k : wvt;
  const unsigned short* Bt = (mode == 0) ? wqt : (mode == 1) ? wkt : a_v;
  const unsigned short* Abase = A + (size_t)m0 * K;
  const unsigned short* Bbase = Bt + (size_t)n0 * K;
  f32x4 acc[8][2] = {};

  // per-thread staging descriptors (source XOR-pre-swizzled, dest linear)
  const unsigned short* ag[4]; int al[4];
  const unsigned short* bg[2]; int bl[2];
#pragma unroll
  for (int i = 0; i < 4; ++i) {
    int c = i * 512 + tid;               // 0..2047: A rows 0..255, 8 chunks/row
    int row = c >> 3, cc = c & 7;
    ag[i] = Abase + (size_t)row * K + ((cc ^ (row & 7)) * 8);
    al[i] = c * 16;
  }
#pragma unroll
  for (int i = 0; i < 2; ++i) {
    int c = i * 512 + tid;               // 0..1023: B rows 0..127
    int row = c >> 3, cc = c & 7;
    bg[i] = Bbase + (size_t)row * K + ((cc ^ (row & 7)) * 8);
    bl[i] = 32768 + c * 16;
  }

  auto stage = [&](int t) {
    char* buf = smem + (t % 3) * BUF;
    int kt = t * 64;
#pragma unroll
    for (int i = 0; i < 4; ++i) gload_lds16(ag[i] + kt, buf + al[i]);
#pragma unroll
    for (int i = 0; i < 2; ++i) gload_lds16(bg[i] + kt, buf + bl[i]);
  };

  stage(0);
  stage(1);

  for (int t = 0; t < NT; ++t) {
    if (t + 2 < NT) {
      stage(t + 2);                                      // 6 loads into buf[(t+2)%3]
      asm volatile("s_waitcnt vmcnt(12)" ::: "memory");  // t+1,t+2 in flight; t landed
    } else if (t + 1 < NT) {
      asm volatile("s_waitcnt vmcnt(6)" ::: "memory");   // t landed; t+1 in flight
    } else {
      asm volatile("s_waitcnt vmcnt(0)" ::: "memory");   // tail drain
    }
    __builtin_amdgcn_s_barrier();        // B1: all waves' tile-t loads drained
    __builtin_amdgcn_sched_barrier(0);
    const unsigned short* sA = (const unsigned short*)(smem + (t % 3) * BUF);
    const unsigned short* sB = (const unsigned short*)(smem + (t % 3) * BUF + 32768);
#pragma unroll
    for (int kk = 0; kk < 2; ++kk) {
      bf16x8 av[8], bv[2];
#pragma unroll
      for (int i = 0; i < 8; ++i) {
        int row = wr * 128 + i * 16 + r15;
        av[i] = *(const bf16x8*)&sA[row * 64 + (((kk * 4 + blk) ^ (row & 7)) * 8)];
      }
#pragma unroll
      for (int j = 0; j < 2; ++j) {
        int row = wc * 32 + j * 16 + r15;
        bv[j] = *(const bf16x8*)&sB[row * 64 + (((kk * 4 + blk) ^ (row & 7)) * 8)];
      }
#pragma unroll
      for (int i = 0; i < 8; ++i)
#pragma unroll
        for (int j = 0; j < 2; ++j) acc[i][j] = MFMA16(av[i], bv[j], acc[i][j]);
    }
    asm volatile("s_waitcnt lgkmcnt(0)" ::: "memory");  // my LDS reads done
    __builtin_amdgcn_s_barrier();        // B2: buf[t%3] safe to overwrite next iter
  }
  __syncthreads();                        // full fence before LDS reuse in epilogue

  if (mode == 2) {
    // V^T: rowg=(h,d), col=(b,s); key s stored at pos (s&~15)|swap23(r15)
    int p15 = (r15 & 3) | ((r15 & 4) << 1) | ((r15 & 8) >> 1);
#pragma unroll
    for (int i = 0; i < 8; ++i)
#pragma unroll
      for (int r = 0; r < 4; ++r) {
        int rowg = m0 + wr * 128 + i * 16 + blk * 4 + r;  // (h,d)
        int h = rowg >> 7, d = rowg & 127;
#pragma unroll
        for (int j = 0; j < 2; ++j) {
          int col = n0 + wc * 32 + j * 16;                // (b, s&~15)
          int b = col >> 11, s16 = col & 2047;
          Vtp[(((size_t)(b * 16 + h) * 128 + d) * 2048) + s16 + p15] = f2bf(acc[i][j][r]);
        }
      }
  } else {
    // LayerNorm over the 128-col tile (= head_dim); head = nt
    float* sSum = (float*)smem;            // [4][256]
    float* sSq  = (float*)smem + 1024;     // [4][256]
#pragma unroll
    for (int i = 0; i < 8; ++i)
#pragma unroll
      for (int r = 0; r < 4; ++r) {
        float v0 = acc[i][0][r], v1 = acc[i][1][r];
        float sm = v0 + v1, sq = v0 * v0 + v1 * v1;
        sm += __shfl_xor(sm, 1); sq += __shfl_xor(sq, 1);
        sm += __shfl_xor(sm, 2); sq += __shfl_xor(sq, 2);
        sm += __shfl_xor(sm, 4); sq += __shfl_xor(sq, 4);
        sm += __shfl_xor(sm, 8); sq += __shfl_xor(sq, 8);
        if (r15 == 0) {
          int rowl = wr * 128 + i * 16 + blk * 4 + r;
          sSum[wc * 256 + rowl] = sm;
          sSq[wc * 256 + rowl] = sq;
        }
      }
    __syncthreads();
    unsigned short* Hout = (mode == 0) ? Qh : Kh;
    const float* lnsc = (mode == 0) ? qls : kls;
    float qmul = (mode == 0) ? (0.08838834764831845f * 1.4426950408889634f) : 1.0f;
    int h = nt;
#pragma unroll
    for (int i = 0; i < 8; ++i)
#pragma unroll
      for (int r = 0; r < 4; ++r) {
        int rowl = wr * 128 + i * 16 + blk * 4 + r;
        float sm = (sSum[rowl] + sSum[256 + rowl]) + (sSum[512 + rowl] + sSum[768 + rowl]);
        float sq = (sSq[rowl] + sSq[256 + rowl]) + (sSq[512 + rowl] + sSq[768 + rowl]);
        float mean = sm * 0.0078125f;
        float var = sq * 0.0078125f - mean * mean;
        float rstd = rsqrtf(var + 1e-6f);
        int rowg = m0 + rowl;
        int b = rowg >> 11, s = rowg & 2047;
        unsigned short* orow = Hout + (((size_t)b * 16 + h) * 2048 + s) * 128;
#pragma unroll
        for (int j = 0; j < 2; ++j) {
          int d = wc * 32 + j * 16 + r15;
          float v = acc[i][j][r];
          v = (v - mean) * rstd * lnsc[d] * qmul;
          orow[d] = f2bf(v);
        }
      }
  }
}

// ---------------- out-proj GEMM: 256x128 tile, tri-buffer ------------------
__global__ __launch_bounds__(512, 2) void k_oproj(const unsigned short* __restrict__ A,
                                                  const unsigned short* __restrict__ Bt,
                                                  float* __restrict__ C) {
  constexpr int K = 2048;
  constexpr int NT = 32;
  constexpr int BUF = 49152;
  __shared__ __attribute__((aligned(16))) char smem[3 * BUF];
  int tid = threadIdx.x;
  int lane = tid & 63, w = tid >> 6;
  int wr = w >> 2, wc = w & 3;
  int r15 = lane & 15, blk = lane >> 4;
  int L = blockIdx.y * gridDim.x + blockIdx.x;
  int xcd = L & 7, slot = L >> 3;
  int mt = xcd * 2 + (slot >> 4), nt = slot & 15;
  int n0 = nt * 128, m0 = mt * 256;
  const unsigned short* Abase = A + (size_t)m0 * K;
  const unsigned short* Bbase = Bt + (size_t)n0 * K;
  f32x4 acc[8][2] = {};

  const unsigned short* ag[4]; int al[4];
  const unsigned short* bg[2]; int bl[2];
#pragma unroll
  for (int i = 0; i < 4; ++i) {
    int c = i * 512 + tid;
    int row = c >> 3, cc = c & 7;
    ag[i] = Abase + (size_t)row * K + ((cc ^ (row & 7)) * 8);
    al[i] = c * 16;
  }
#pragma unroll
  for (int i = 0; i < 2; ++i) {
    int c = i * 512 + tid;
    int row = c >> 3, cc = c & 7;
    bg[i] = Bbase + (size_t)row * K + ((cc ^ (row & 7)) * 8);
    bl[i] = 32768 + c * 16;
  }

  auto stage = [&](int t) {
    char* buf = smem + (t % 3) * BUF;
    int kt = t * 64;
#pragma unroll
    for (int i = 0; i < 4; ++i) gload_lds16(ag[i] + kt, buf + al[i]);
#pragma unroll
    for (int i = 0; i < 2; ++i) gload_lds16(bg[i] + kt, buf + bl[i]);
  };

  stage(0);
  stage(1);

  for (int t = 0; t < NT; ++t) {
    if (t + 2 < NT) {
      stage(t + 2);
      asm volatile("s_waitcnt vmcnt(12)" ::: "memory");
    } else if (t + 1 < NT) {
      asm volatile("s_waitcnt vmcnt(6)" ::: "memory");
    } else {
      asm volatile("s_waitcnt vmcnt(0)" ::: "memory");
    }
    __builtin_amdgcn_s_barrier();
    __builtin_amdgcn_sched_barrier(0);
    const unsigned short* sA = (const unsigned short*)(smem + (t % 3) * BUF);
    const unsigned short* sB = (const unsigned short*)(smem + (t % 3) * BUF + 32768);
#pragma unroll
    for (int kk = 0; kk < 2; ++kk) {
      bf16x8 av[8], bv[2];
#pragma unroll
      for (int i = 0; i < 8; ++i) {
        int row = wr * 128 + i * 16 + r15;
        av[i] = *(const bf16x8*)&sA[row * 64 + (((kk * 4 + blk) ^ (row & 7)) * 8)];
      }
#pragma unroll
      for (int j = 0; j < 2; ++j) {
        int row = wc * 32 + j * 16 + r15;
        bv[j] = *(const bf16x8*)&sB[row * 64 + (((kk * 4 + blk) ^ (row & 7)) * 8)];
      }
#pragma unroll
      for (int i = 0; i < 8; ++i)
#pragma unroll
        for (int j = 0; j < 2; ++j) acc[i][j] = MFMA16(av[i], bv[j], acc[i][j]);
    }
    asm volatile("s_waitcnt lgkmcnt(0)" ::: "memory");
    __builtin_amdgcn_s_barrier();
  }

#pragma unroll
  for (int i = 0; i < 8; ++i)
#pragma unroll
    for (int r = 0; r < 4; ++r) {
      int rowl = wr * 128 + i * 16 + blk * 4 + r;
#pragma unroll
      for (int j = 0; j < 2; ++j) {
        int coll = wc * 32 + j * 16 + r15;
        C[(size_t)(m0 + rowl) * 2048 + n0 + coll] = acc[i][j][r];
      }
    }
}

// ---------------- flash attention: 32x32x16 MFMA, XCD-clustered ------------
// 4 waves x 32 q = QBLK 128; KVBLK=64; dbuf 64 KB; grid 512 -> 2 blocks/CU.
__global__ __launch_bounds__(256, 2) void k_attn(const unsigned short* __restrict__ Qh,
                                                 const unsigned short* __restrict__ Kh,
                                                 const unsigned short* __restrict__ Vtp,
                                                 const unsigned* __restrict__ maskb,
                                                 unsigned short* __restrict__ O) {
  __shared__ __attribute__((aligned(16))) char smem[65536];  // 2 x (sK 16K + sV 16K)
  int tid = threadIdx.x, w = tid >> 6;
  int lane = tid & 63;
  int q31 = lane & 31, hi = lane >> 5;
  // XCD-clustered remap (bijective: grid = 16 x 32 = 512)
  int L = blockIdx.y * 16 + blockIdx.x;
  int xcd = L & 7, slot = L >> 3;        // slot 0..63
  int bh = xcd * 4 + (slot >> 4);
  int qb = (slot & 15) * 128;
  int b = bh >> 4, h = bh & 15;
  size_t base = (size_t)bh * (2048 * 128);
  int qrow = qb + w * 32 + q31;

  bf16x8 qf[8];  // Q (B-operand): col=q31, k-window wd: d = wd*16 + hi*8 + j
  {
    const unsigned short* qp = Qh + base + (size_t)qrow * 128 + hi * 8;
#pragma unroll
    for (int wd = 0; wd < 8; ++wd) qf[wd] = *(const bf16x8*)(qp + wd * 16);
  }
  const unsigned* mrow = maskb + ((size_t)b * 2048 + qrow) * 64;

  // staging bases (kc=0): K [64 keys][128 d] linear rows, V^T [128 d][64 pos]
  const unsigned short* kgp[4];
  const unsigned short* vgp[4];
#pragma unroll
  for (int i = 0; i < 4; ++i) {
    int c = i * 256 + tid;              // 0..1023 chunk id
    int rr = c >> 4, cc = c & 15;       // K: row rr, 16B chunk cc
    kgp[i] = Kh + base + (size_t)rr * 128 + ((cc ^ (rr & 15)) * 8);
    int d = c >> 3, c8 = c & 7;         // V: row d, chunk c8
    vgp[i] = Vtp + base + (size_t)d * 2048 + ((c8 ^ (d & 7)) * 8);
  }

  f32x16 o[4] = {};                     // o[dt]: col d = dt*32+q31, rows=q slots
  float mv = -1e30f, ls = 0.f;

  // prologue: stage tile 0 into buf 0
#pragma unroll
  for (int i = 0; i < 4; ++i) {
    int c = i * 256 + tid;
    gload_lds16(kgp[i], smem + c * 16);
    gload_lds16(vgp[i], smem + 16384 + c * 16);
  }
  __syncthreads();

  int cur = 0;
  for (int kc = 0; kc < 2048; kc += 64) {
    if (kc + 64 < 2048) {  // stage next tile into the other buffer
      char* nb = smem + ((cur ^ 1) << 15);
#pragma unroll
      for (int i = 0; i < 4; ++i) {
        int c = i * 256 + tid;
        gload_lds16(kgp[i] + (size_t)(kc + 64) * 128, nb + c * 16);
        gload_lds16(vgp[i] + (kc + 64), nb + 16384 + c * 16);
      }
    }
    const unsigned short* sK = (const unsigned short*)(smem + (cur << 15));
    const unsigned short* sV = (const unsigned short*)(smem + (cur << 15) + 16384);

    unsigned mw0 = mrow[kc >> 5] >> (4 * hi);
    unsigned mw1 = mrow[(kc >> 5) + 1] >> (4 * hi);

    // S^T: 2 key-tiles x 8 d-windows. A=K frag: row=key=q31 (lane pos), k-window wd
    f32x16 st0 = {}, st1 = {};
#pragma unroll
    for (int wd = 0; wd < 8; ++wd) {
      int ck = ((2 * wd + hi) ^ (q31 & 15)) * 8;
      bf16x8 k0 = *(const bf16x8*)&sK[q31 * 128 + ck];
      bf16x8 k1 = *(const bf16x8*)&sK[(32 + q31) * 128 + ck];
      st0 = MFMA32(k0, qf[wd], st0);
      st1 = MFMA32(k1, qf[wd], st1);
    }

    // mask: slot r of tile kt = key kt*32 + (r&3)+8*(r>>2)+4*hi
    float pvv[32];
#pragma unroll
    for (int r = 0; r < 16; ++r) {
      int bit = (r & 3) + 8 * (r >> 2);  // compile-time
      pvv[r] = ((mw0 >> bit) & 1u) ? st0[r] : -1e30f;
      pvv[16 + r] = ((mw1 >> bit) & 1u) ? st1[r] : -1e30f;
    }
    // max over 32 slots (tree)
    float c0 = max3f(pvv[0], pvv[1], pvv[2]);
    float c1 = max3f(pvv[3], pvv[4], pvv[5]);
    float c2 = max3f(pvv[6], pvv[7], pvv[8]);
    float c3 = max3f(pvv[9], pvv[10], pvv[11]);
    float c4 = max3f(pvv[12], pvv[13], pvv[14]);
    float c5 = max3f(pvv[15], pvv[16], pvv[17]);
    float c6 = max3f(pvv[18], pvv[19], pvv[20]);
    float c7 = max3f(pvv[21], pvv[22], pvv[23]);
    float c8 = max3f(pvv[24], pvv[25], pvv[26]);
    float c9 = max3f(pvv[27], pvv[28], pvv[29]);
    float ca = fmaxf(pvv[30], pvv[31]);
    float t0 = max3f(c0, c1, c2);
    float t1 = max3f(c3, c4, c5);
    float t2 = max3f(c6, c7, c8);
    float t3 = max3f(c9, ca, t0);
    float cmax = max3f(t1, t2, t3);
    cmax = fmaxf(cmax, __shfl_xor(cmax, 32));

    if (!__all(cmax - mv <= 11.5f)) {  // defer-max: P bounded by 2^11.5
      float mnew = fmaxf(mv, cmax);
      float fac = exp2a(mv - mnew);
      ls *= fac;
      float fr[16];
#pragma unroll
      for (int r = 0; r < 16; ++r) fr[r] = __shfl(fac, (r & 3) + 8 * (r >> 2) + 4 * hi);
#pragma unroll
      for (int dt = 0; dt < 4; ++dt)
#pragma unroll
        for (int r = 0; r < 16; ++r) o[dt][r] *= fr[r];
      mv = mnew;
    }

#pragma unroll
    for (int t = 0; t < 32; ++t) pvv[t] = exp2a(pvv[t] - mv);
    {
      float s0 = 0.f, s1 = 0.f, s2 = 0.f, s3 = 0.f;
#pragma unroll
      for (int t = 0; t < 8; ++t) {
        s0 += pvv[t]; s1 += pvv[8 + t]; s2 += pvv[16 + t]; s3 += pvv[24 + t];
      }
      ls += (s0 + s1) + (s2 + s3);
    }

    // packs: window kw covers pvv[8*kw .. 8*kw+7] (= keys kw*16 + sigma(hi,j))
    bf16x8 pa[4];
#pragma unroll
    for (int kw = 0; kw < 4; ++kw) {
      uint4v pw;
#pragma unroll
      for (int m = 0; m < 4; ++m) pw[m] = pkbf(pvv[8 * kw + 2 * m], pvv[8 * kw + 2 * m + 1]);
      pa[kw] = __builtin_bit_cast(bf16x8, pw);
    }

    // PV: o[dt] += P(window kw) x V; B-frag = sV row dt*32+q31, chunk (2kw+hi)
#pragma unroll
    for (int dt = 0; dt < 4; ++dt) {
      int vrow = dt * 32 + q31;
#pragma unroll
      for (int kw = 0; kw < 4; ++kw) {
        int cv = ((2 * kw + hi) ^ (q31 & 7)) * 8;
        bf16x8 vf = *(const bf16x8*)&sV[vrow * 64 + cv];
        o[dt] = MFMA32(pa[kw], vf, o[dt]);
      }
    }
    __syncthreads();
    cur ^= 1;
  }

  // normalize factors: partner lane (l^32) holds the other half of the keys
  ls += __shfl_xor(ls, 32);
  float inv = 1.f / ls;
  float ir[16];
#pragma unroll
  for (int r = 0; r < 16; ++r) ir[r] = __shfl(inv, (r & 3) + 8 * (r >> 2) + 4 * hi);

  // epilogue: two 64-row passes through sO overlay (waves 0-1, then 2-3)
  float* sO = (float*)smem;
#pragma unroll
  for (int pass = 0; pass < 2; ++pass) {
    __syncthreads();
    if ((w >> 1) == pass) {
      int wl = w & 1;
#pragma unroll
      for (int dt = 0; dt < 4; ++dt)
#pragma unroll
        for (int r = 0; r < 16; ++r) {
          int qrl = wl * 32 + (r & 3) + 8 * (r >> 2) + 4 * hi;
          sO[qrl * 132 + dt * 32 + q31] = o[dt][r] * ir[r];
        }
    }
    __syncthreads();
    {
      int row = tid >> 2, d0 = (tid & 3) * 32;
      int grow = qb + pass * 64 + row;
      unsigned short* op = O + (size_t)(b * 2048 + grow) * 2048 + h * 128 + d0;
#pragma unroll
      for (int g = 0; g < 4; ++g) {
        ushort8 pk;
#pragma unroll
        for (int e = 0; e < 8; ++e) pk[e] = f2bf(sO[row * 132 + d0 + g * 8 + e]);
        *(ushort8*)(op + g * 8) = pk;
      }
    }
  }
}

// ---------------------------------------------------------------------------
extern "C" void kernel_launch(void* const* d_in, const int* in_sizes, int n_in,
                              void* d_out, int out_size, void* d_ws, size_t ws_size,
                              hipStream_t stream) {
  const float* q      = (const float*)d_in[0];
  const float* kv     = (const float*)d_in[1];
  const float* q_pos  = (const float*)d_in[2];
  const float* kv_pos = (const float*)d_in[3];
  const int*   mask   = (const int*)d_in[4];
  const float* wq     = (const float*)d_in[5];
  const float* wk     = (const float*)d_in[6];
  const float* wv     = (const float*)d_in[7];
  const float* qls    = (const float*)d_in[8];
  const float* kls    = (const float*)d_in[9];
  const float* wo     = (const float*)d_in[10];

  char* ws = (char*)d_ws;
  const size_t SZ_ACT = (size_t)4096 * 2048 * 2;  // 16 MiB
  const size_t SZ_W   = (size_t)2048 * 2048 * 2;  // 8 MiB
  unsigned short* a_q = (unsigned short*)(ws);
  unsigned short* a_k = (unsigned short*)(ws + SZ_ACT);
  unsigned short* a_v = (unsigned short*)(ws + 2 * SZ_ACT);
  unsigned short* Qh  = (unsigned short*)(ws + 3 * SZ_ACT);
  unsigned short* Kh  = (unsigned short*)(ws + 4 * SZ_ACT);
  unsigned short* wqt = (unsigned short*)(ws + 6 * SZ_ACT);
  unsigned short* wkt = (unsigned short*)(ws + 6 * SZ_ACT + SZ_W);
  unsigned short* wvt = (unsigned short*)(ws + 6 * SZ_ACT + 2 * SZ_W);
  unsigned short* wot = (unsigned short*)(ws + 6 * SZ_ACT + 3 * SZ_W);
  unsigned*       mkb = (unsigned*)(ws + 6 * SZ_ACT + 4 * SZ_W);
  unsigned short* Ob  = a_q;  // a_q dead after Q-projection; reuse for attn out
  unsigned short* Vtr = (unsigned short*)(ws + 5 * SZ_ACT);  // V^T

  const size_t NEED = 6 * SZ_ACT + 4 * SZ_W + (size_t)2 * 2048 * 64 * 4;
  if (ws_size < NEED) return;  // leave d_out poisoned -> visible failure

  k_prep<<<32768, 256, 0, stream>>>((const float4v*)q, (const float4v*)q_pos,
                                    (const float4v*)kv, (const float4v*)kv_pos, mask,
                                    (ushort4v*)a_q, (ushort4v*)a_k, (ushort4v*)a_v,
                                    (unsigned long long*)mkb,
                                    wq, wk, wv, wo, wqt, wkt, wvt, wot);

  // merged Q/K/V^T projections: 3 x 256 blocks in one launch
  k_qkv<<<768, 512, 0, stream>>>(a_q, wqt, Qh, qls, a_k, wkt, Kh, kls, wvt, a_v, Vtr);

  k_attn<<<dim3(16, 32), 256, 0, stream>>>(Qh, Kh, Vtr, mkb, Ob);

  // out-proj: M=4096, N=2048 -> fp32 d_out
  k_oproj<<<dim3(16, 16), 512, 0, stream>>>(Ob, wot, (float*)d_out);
}